// Round 4
// baseline (795.421 us; speedup 1.0000x reference)
//
#include <hip/hip_runtime.h>

// BetaBernoulliMixture, output [5, B, T] = {a1, b1, a2, b2, post_mixweight}
//   a1 = A1+s_prev, b1 = B1+f_prev, a2 = A2+s_prev, b2 = B2+f_prev
//   pm = w / (w + (1-w)*exp(d)),  d(t) = sum_{u<t} log(sel2_u*(AB1+u)) - log(sel1_u*(AB2+u))
//
// Experiment ledger (kernel-only = dur_us - ~430us harness fill):
//   R3 block/row 256thr + NT ............. ~330us
//   R4 wave/row, 0 barriers + NT ......... ~330us  (sync exonerated)
//   R5 block/row 1024thr, 16KB bursts .... ~310us  (footprint/burst exonerated)
//   R6 = R5 with plain cached stores ..... ~308us  (NT path exonerated)
// Prev session: removing 2x write amplification saved ~140us -> kernel DOES
// respond to traffic at ~4.8 TB/s marginal => ~305us attribution is real.
// Remaining invariant: every worker writes 5 concurrent streams at exactly
// 128MiB (2^27) stride -> identical addr bits [0:26] -> same channel+bank,
// 5 different DRAM rows -> per-bank row thrash; chip-wide thousands of
// scattered fronts vs the fill's single 6.2TB/s sweep.
//
// R7: PLANE-SPLIT. grid = 5*B; block (row,plane) computes ONE plane of ONE
// row: 1 contiguous read + 1 contiguous write stream per block. obs re-read
// 5x but the 5 readers of row r are dispatch-adjacent (bid=row*5+plane) and
// obs (134MB) < LLC (256MiB) -> re-reads are Infinity-Cache hits, HBM
// traffic unchanged (~805MB). Planes 0-3 are affine in the ballot s-scan
// (no logs); only plane 4 (pm) runs the d-scan + transcendentals.
// 256 threads, 4 waves, parity-double-buffered LDS partials.

#define BLOCK 256
#define VEC 4
#define NW (BLOCK / 64)   // 4 waves

typedef float v4f __attribute__((ext_vector_type(4)));

__global__ __launch_bounds__(BLOCK) void bbm_kernel(
    const float* __restrict__ obs,
    const float* __restrict__ alpha1, const float* __restrict__ beta1,
    const float* __restrict__ alpha2, const float* __restrict__ beta2,
    const float* __restrict__ mixw,
    float* __restrict__ out,
    int T, size_t bt)
{
    const int bid   = blockIdx.x;
    const int row   = bid / 5;
    const int plane = bid - row * 5;
    const int tid   = threadIdx.x;
    const int lane  = tid & 63;
    const int wid   = tid >> 6;

    __shared__ int   sPart[2][NW];
    __shared__ float dPart[2][NW];

    const float* __restrict__ orow = obs + (size_t)row * T;
    float* __restrict__ prow = out + (size_t)plane * bt + (size_t)row * T;

    const unsigned long long lt_mask = ((unsigned long long)1 << lane) - 1ull;

    const int EPB   = BLOCK * VEC;   // 1024 elements per iteration
    const int iters = T / EPB;       // 8 for T=8192

    // preload first chunk (thread-contiguous float4)
    v4f cur = *(const v4f*)(orow + tid * VEC);

    if (plane < 4) {
        // ---------- affine planes: only the s-scan, one store stream ----------
        const float A1 = alpha1[row], B1 = beta1[row];
        const float A2 = alpha2[row], B2 = beta2[row];
        const float c0 = (plane == 0) ? A1 : (plane == 1) ? B1
                       : (plane == 2) ? A2 : B2;
        const bool use_s = (plane & 1) == 0;   // a1,a2 use fs; b1,b2 use fp

        int carry_s = 0;
        for (int it = 0; it < iters; ++it) {
            const int t0 = it * EPB + tid * VEC;
            const int pb = it & 1;

            v4f nxt;
            if (it + 1 < iters) nxt = *(const v4f*)(orow + (it + 1) * EPB + tid * VEC);

            int bit[VEC], sloc[VEC];
            int ts = 0;
            #pragma unroll
            for (int j = 0; j < VEC; ++j) { bit[j] = cur[j] > 0.5f; sloc[j] = ts; ts += bit[j]; }

            unsigned long long m0 = __ballot(bit[0]);
            unsigned long long m1 = __ballot(bit[1]);
            unsigned long long m2 = __ballot(bit[2]);
            unsigned long long m3 = __ballot(bit[3]);
            const int wave_excl = __builtin_popcountll(m0 & lt_mask)
                                + __builtin_popcountll(m1 & lt_mask)
                                + __builtin_popcountll(m2 & lt_mask)
                                + __builtin_popcountll(m3 & lt_mask);
            const int wave_tot  = __builtin_popcountll(m0) + __builtin_popcountll(m1)
                                + __builtin_popcountll(m2) + __builtin_popcountll(m3);
            if (lane == 0) sPart[pb][wid] = wave_tot;
            __syncthreads();
            int prior = 0, total = 0;
            #pragma unroll
            for (int wI = 0; wI < NW; ++wI) {
                int p = sPart[pb][wI];
                total += p;
                if (wI < wid) prior += p;
            }
            const int tbase_s = carry_s + prior + wave_excl;

            v4f o;
            #pragma unroll
            for (int j = 0; j < VEC; ++j) {
                const float ft = (float)(t0 + j);
                const float fs = (float)(tbase_s + sloc[j]);
                o[j] = use_s ? (c0 + fs) : (c0 + (ft - fs));
            }
            *(v4f*)(prow + t0) = o;

            carry_s += total;
            cur = nxt;
        }
    } else {
        // ---------- pm plane: s-scan + d-scan + transcendentals ----------
        const float A1 = alpha1[row], B1 = beta1[row];
        const float A2 = alpha2[row], B2 = beta2[row];
        const float w  = mixw[0];
        const float AB1 = A1 + B1, AB2 = A2 + B2;
        const float w2 = 1.0f - w;

        int   carry_s = 0;
        float carry_d = 0.0f;

        for (int it = 0; it < iters; ++it) {
            const int t0 = it * EPB + tid * VEC;
            const int pb = it & 1;

            v4f nxt;
            if (it + 1 < iters) nxt = *(const v4f*)(orow + (it + 1) * EPB + tid * VEC);

            int bit[VEC], sloc[VEC];
            int ts = 0;
            #pragma unroll
            for (int j = 0; j < VEC; ++j) { bit[j] = cur[j] > 0.5f; sloc[j] = ts; ts += bit[j]; }

            unsigned long long m0 = __ballot(bit[0]);
            unsigned long long m1 = __ballot(bit[1]);
            unsigned long long m2 = __ballot(bit[2]);
            unsigned long long m3 = __ballot(bit[3]);
            const int wave_excl = __builtin_popcountll(m0 & lt_mask)
                                + __builtin_popcountll(m1 & lt_mask)
                                + __builtin_popcountll(m2 & lt_mask)
                                + __builtin_popcountll(m3 & lt_mask);
            const int wave_tot  = __builtin_popcountll(m0) + __builtin_popcountll(m1)
                                + __builtin_popcountll(m2) + __builtin_popcountll(m3);
            if (lane == 0) sPart[pb][wid] = wave_tot;
            __syncthreads();
            int prior = 0, total = 0;
            #pragma unroll
            for (int wI = 0; wI < NW; ++wI) {
                int p = sPart[pb][wI];
                total += p;
                if (wI < wid) prior += p;
            }
            const int tbase_s = carry_s + prior + wave_excl;

            float dloc[VEC];
            float td = 0.0f;
            #pragma unroll
            for (int j = 0; j < VEC; ++j) {
                const float ft = (float)(t0 + j);
                const float fs = (float)(tbase_s + sloc[j]);
                const float fp = ft - fs;
                const float sel1 = bit[j] ? (A1 + fs) : (B1 + fp);
                const float sel2 = bit[j] ? (A2 + fs) : (B2 + fp);
                const float delta = __logf(sel2 * (AB1 + ft)) - __logf(sel1 * (AB2 + ft));
                dloc[j] = td;
                td += delta;
            }

            float incl_d = td;
            #pragma unroll
            for (int off = 1; off < 64; off <<= 1) {
                float n = __shfl_up(incl_d, off, 64);
                if (lane >= off) incl_d += n;
            }
            if (lane == 63) dPart[pb][wid] = incl_d;
            __syncthreads();
            float priord = 0.0f, totald = 0.0f;
            #pragma unroll
            for (int wI = 0; wI < NW; ++wI) {
                float p = dPart[pb][wI];
                totald += p;
                if (wI < wid) priord += p;
            }
            const float tbase_d = carry_d + priord + (incl_d - td);

            v4f o;
            #pragma unroll
            for (int j = 0; j < VEC; ++j) {
                const float d = tbase_d + dloc[j];
                o[j] = __fdividef(w, w + w2 * __expf(d));
            }
            *(v4f*)(prow + t0) = o;

            carry_s += total;
            carry_d += totald;
            cur = nxt;
        }
    }
}

extern "C" void kernel_launch(void* const* d_in, const int* in_sizes, int n_in,
                              void* d_out, int out_size, void* d_ws, size_t ws_size,
                              hipStream_t stream) {
    const float* obs    = (const float*)d_in[0];
    const float* alpha1 = (const float*)d_in[1];
    const float* beta1  = (const float*)d_in[2];
    const float* alpha2 = (const float*)d_in[3];
    const float* beta2  = (const float*)d_in[4];
    const float* mixw   = (const float*)d_in[5];

    const int Bn = in_sizes[1];
    const int Tn = in_sizes[0] / Bn;
    const size_t bt = (size_t)Bn * (size_t)Tn;

    bbm_kernel<<<Bn * 5, BLOCK, 0, stream>>>(obs, alpha1, beta1, alpha2, beta2,
                                             mixw, (float*)d_out, Tn, bt);
}

// Round 5
// 742.129 us; speedup vs baseline: 1.0718x; 1.0718x over previous
//
#include <hip/hip_runtime.h>

// BetaBernoulliMixture, output [5, B, T] = {a1, b1, a2, b2, post_mixweight}
//
// Ledger (kernel-only = dur_us - ~430us harness fill; traffic floor 805MB
// -> 128us @ 6.3 TB/s):
//   R3 block/row 256thr + NT .......... ~330us
//   R4 wave/row, 0 barriers ........... ~330us  (sync exonerated)
//   R5 1024thr, 16KB bursts ........... ~310us  (footprint/burst exonerated)
//   R6 plain cached stores ............ ~308us  (NT exonerated)
//   R7 plane-split (1 stream/block) ... ~365us  (REGRESSED: 5x obs re-read
//      via per-XCD L2s + pm load imbalance; confounded de-alias test)
// Marginal traffic rate is ~4.8 TB/s (prev-session R2->R3: -670MB = -140us)
// yet average is ~2.6 -> pattern throttle suspected.
//
// R8: PHASE-LAGGED STORES on the R3/R6 structure. The one invariant never
// isolated: all 5 stores per thread/iteration share address bits [0:26]
// (plane stride 2^27) and are issued together -> same L2 set-region, same
// DRAM column bits, 5x churn in one set while others idle; dirty evictions
// leave in bursts of 5 same-bank lines. Fix: store plane p lagged by p
// segments (register FIFOs, statically indexed via full unroll, SEGS=8) so
// the 5 concurrent store fronts sit at 5 DIFFERENT intra-row offsets
// (distinct bits [12:15]). Same values, same traffic, same instruction mix
// -- only the temporal alignment of store addresses changes.

#define BLOCK 256
#define VEC 4
#define NW (BLOCK / 64)   // 4 waves

typedef float v4f __attribute__((ext_vector_type(4)));

template <int SEGS>
__global__ __launch_bounds__(BLOCK) void bbm_lag(
    const float* __restrict__ obs,
    const float* __restrict__ alpha1, const float* __restrict__ beta1,
    const float* __restrict__ alpha2, const float* __restrict__ beta2,
    const float* __restrict__ mixw,
    float* __restrict__ out,
    int T, size_t bt)
{
    const int row  = blockIdx.x;
    const int tid  = threadIdx.x;
    const int lane = tid & 63;
    const int wid  = tid >> 6;

    __shared__ int   sPart[2][NW];
    __shared__ float dPart[2][NW];

    const float A1 = alpha1[row], B1 = beta1[row];
    const float A2 = alpha2[row], B2 = beta2[row];
    const float w  = mixw[0];
    const float AB1 = A1 + B1, AB2 = A2 + B2;
    const float w2 = 1.0f - w;

    const float* __restrict__ orow = obs + (size_t)row * T;
    float* __restrict__ obase = out + (size_t)row * T;

    const unsigned long long lt_mask = ((unsigned long long)1 << lane) - 1ull;

    int   carry_s = 0;
    float carry_d = 0.0f;

    const int EPB = BLOCK * VEC;     // 1024 elements per segment

    // plane-lag FIFOs: plane p lags p segments. Statically indexed (full
    // unroll) -> registers, not scratch. (s-p)%p == s%p for the push/pop
    // slot, so store-then-overwrite in the same slot is correct.
    v4f fb1[1], fa2[2], fb2[3], fpm[4];

    v4f cur = *(const v4f*)(orow + tid * VEC);

    #pragma unroll
    for (int s = 0; s < SEGS + 4; ++s) {
        v4f va1, vb1n, va2n, vb2n, vpmn;

        if (s < SEGS) {
            const int t0 = s * EPB + tid * VEC;
            const int pb = s & 1;

            v4f nxt;
            if (s + 1 < SEGS) nxt = *(const v4f*)(orow + (s + 1) * EPB + tid * VEC);

            int bit[VEC], sloc[VEC];
            int ts = 0;
            #pragma unroll
            for (int j = 0; j < VEC; ++j) { bit[j] = cur[j] > 0.5f; sloc[j] = ts; ts += bit[j]; }

            unsigned long long m0 = __ballot(bit[0]);
            unsigned long long m1 = __ballot(bit[1]);
            unsigned long long m2 = __ballot(bit[2]);
            unsigned long long m3 = __ballot(bit[3]);
            const int wave_excl = __builtin_popcountll(m0 & lt_mask)
                                + __builtin_popcountll(m1 & lt_mask)
                                + __builtin_popcountll(m2 & lt_mask)
                                + __builtin_popcountll(m3 & lt_mask);
            const int wave_tot  = __builtin_popcountll(m0) + __builtin_popcountll(m1)
                                + __builtin_popcountll(m2) + __builtin_popcountll(m3);
            if (lane == 0) sPart[pb][wid] = wave_tot;
            __syncthreads();
            int prior = 0, total = 0;
            #pragma unroll
            for (int wI = 0; wI < NW; ++wI) {
                int p = sPart[pb][wI];
                total += p;
                if (wI < wid) prior += p;
            }
            const int tbase_s = carry_s + prior + wave_excl;

            float dloc[VEC];
            float td = 0.0f;
            #pragma unroll
            for (int j = 0; j < VEC; ++j) {
                const float ft = (float)(t0 + j);
                const float fs = (float)(tbase_s + sloc[j]);
                const float fp = ft - fs;
                const float sel1 = bit[j] ? (A1 + fs) : (B1 + fp);
                const float sel2 = bit[j] ? (A2 + fs) : (B2 + fp);
                const float delta = __logf(sel2 * (AB1 + ft)) - __logf(sel1 * (AB2 + ft));
                dloc[j] = td;
                td += delta;
            }

            float incl_d = td;
            #pragma unroll
            for (int off = 1; off < 64; off <<= 1) {
                float n = __shfl_up(incl_d, off, 64);
                if (lane >= off) incl_d += n;
            }
            if (lane == 63) dPart[pb][wid] = incl_d;
            __syncthreads();
            float priord = 0.0f, totald = 0.0f;
            #pragma unroll
            for (int wI = 0; wI < NW; ++wI) {
                float p = dPart[pb][wI];
                totald += p;
                if (wI < wid) priord += p;
            }
            const float tbase_d = carry_d + priord + (incl_d - td);

            #pragma unroll
            for (int j = 0; j < VEC; ++j) {
                const float ft = (float)(t0 + j);
                const float fs = (float)(tbase_s + sloc[j]);
                const float fp = ft - fs;
                const float d  = tbase_d + dloc[j];
                va1[j]  = A1 + fs;
                vb1n[j] = B1 + fp;
                va2n[j] = A2 + fs;
                vb2n[j] = B2 + fp;
                vpmn[j] = __fdividef(w, w + w2 * __expf(d));
            }
            // plane 0 stores in-phase
            *(v4f*)(obase + t0) = va1;

            carry_s += total;
            carry_d += totald;
            cur = nxt;
        }

        // lagged stores: plane p writes segment s-p (store before push —
        // same FIFO slot since (s-p)%p == s%p)
        if (s - 1 >= 0 && s - 1 < SEGS)
            *(v4f*)(obase + bt     + (size_t)(s - 1) * EPB + tid * VEC) = fb1[0];
        if (s - 2 >= 0 && s - 2 < SEGS)
            *(v4f*)(obase + 2 * bt + (size_t)(s - 2) * EPB + tid * VEC) = fa2[s & 1];
        if (s - 3 >= 0 && s - 3 < SEGS)
            *(v4f*)(obase + 3 * bt + (size_t)(s - 3) * EPB + tid * VEC) = fb2[s % 3];
        if (s - 4 >= 0 && s - 4 < SEGS)
            *(v4f*)(obase + 4 * bt + (size_t)(s - 4) * EPB + tid * VEC) = fpm[s & 3];

        if (s < SEGS) {
            fb1[0]     = vb1n;
            fa2[s & 1] = va2n;
            fb2[s % 3] = vb2n;
            fpm[s & 3] = vpmn;
        }
    }
}

// Generic fallback (R6-style in-phase stores), any T % 1024 == 0
__global__ __launch_bounds__(BLOCK) void bbm_kernel(
    const float* __restrict__ obs,
    const float* __restrict__ alpha1, const float* __restrict__ beta1,
    const float* __restrict__ alpha2, const float* __restrict__ beta2,
    const float* __restrict__ mixw,
    float* __restrict__ out,
    int T, size_t bt)
{
    const int row  = blockIdx.x;
    const int tid  = threadIdx.x;
    const int lane = tid & 63;
    const int wid  = tid >> 6;

    __shared__ int   sPart[2][NW];
    __shared__ float dPart[2][NW];

    const float A1 = alpha1[row], B1 = beta1[row];
    const float A2 = alpha2[row], B2 = beta2[row];
    const float w  = mixw[0];
    const float AB1 = A1 + B1, AB2 = A2 + B2;
    const float w2 = 1.0f - w;

    const float* __restrict__ orow = obs + (size_t)row * T;
    float* __restrict__ obase = out + (size_t)row * T;

    const unsigned long long lt_mask = ((unsigned long long)1 << lane) - 1ull;

    int   carry_s = 0;
    float carry_d = 0.0f;

    const int EPB  = BLOCK * VEC;
    const int segs = T / EPB;

    v4f cur = *(const v4f*)(orow + tid * VEC);

    for (int s = 0; s < segs; ++s) {
        const int t0 = s * EPB + tid * VEC;
        const int pb = s & 1;

        v4f nxt;
        if (s + 1 < segs) nxt = *(const v4f*)(orow + (s + 1) * EPB + tid * VEC);

        int bit[VEC], sloc[VEC];
        int ts = 0;
        #pragma unroll
        for (int j = 0; j < VEC; ++j) { bit[j] = cur[j] > 0.5f; sloc[j] = ts; ts += bit[j]; }

        unsigned long long m0 = __ballot(bit[0]);
        unsigned long long m1 = __ballot(bit[1]);
        unsigned long long m2 = __ballot(bit[2]);
        unsigned long long m3 = __ballot(bit[3]);
        const int wave_excl = __builtin_popcountll(m0 & lt_mask)
                            + __builtin_popcountll(m1 & lt_mask)
                            + __builtin_popcountll(m2 & lt_mask)
                            + __builtin_popcountll(m3 & lt_mask);
        const int wave_tot  = __builtin_popcountll(m0) + __builtin_popcountll(m1)
                            + __builtin_popcountll(m2) + __builtin_popcountll(m3);
        if (lane == 0) sPart[pb][wid] = wave_tot;
        __syncthreads();
        int prior = 0, total = 0;
        #pragma unroll
        for (int wI = 0; wI < NW; ++wI) {
            int p = sPart[pb][wI];
            total += p;
            if (wI < wid) prior += p;
        }
        const int tbase_s = carry_s + prior + wave_excl;

        float dloc[VEC];
        float td = 0.0f;
        #pragma unroll
        for (int j = 0; j < VEC; ++j) {
            const float ft = (float)(t0 + j);
            const float fs = (float)(tbase_s + sloc[j]);
            const float fp = ft - fs;
            const float sel1 = bit[j] ? (A1 + fs) : (B1 + fp);
            const float sel2 = bit[j] ? (A2 + fs) : (B2 + fp);
            const float delta = __logf(sel2 * (AB1 + ft)) - __logf(sel1 * (AB2 + ft));
            dloc[j] = td;
            td += delta;
        }

        float incl_d = td;
        #pragma unroll
        for (int off = 1; off < 64; off <<= 1) {
            float n = __shfl_up(incl_d, off, 64);
            if (lane >= off) incl_d += n;
        }
        if (lane == 63) dPart[pb][wid] = incl_d;
        __syncthreads();
        float priord = 0.0f, totald = 0.0f;
        #pragma unroll
        for (int wI = 0; wI < NW; ++wI) {
            float p = dPart[pb][wI];
            totald += p;
            if (wI < wid) priord += p;
        }
        const float tbase_d = carry_d + priord + (incl_d - td);

        v4f va1, vb1, va2, vb2, vpm;
        #pragma unroll
        for (int j = 0; j < VEC; ++j) {
            const float ft = (float)(t0 + j);
            const float fs = (float)(tbase_s + sloc[j]);
            const float fp = ft - fs;
            const float d  = tbase_d + dloc[j];
            va1[j] = A1 + fs;
            vb1[j] = B1 + fp;
            va2[j] = A2 + fs;
            vb2[j] = B2 + fp;
            vpm[j] = __fdividef(w, w + w2 * __expf(d));
        }
        float* p = obase + t0;
        *(v4f*)(p)          = va1;
        *(v4f*)(p + bt)     = vb1;
        *(v4f*)(p + 2 * bt) = va2;
        *(v4f*)(p + 3 * bt) = vb2;
        *(v4f*)(p + 4 * bt) = vpm;

        carry_s += total;
        carry_d += totald;
        cur = nxt;
    }
}

extern "C" void kernel_launch(void* const* d_in, const int* in_sizes, int n_in,
                              void* d_out, int out_size, void* d_ws, size_t ws_size,
                              hipStream_t stream) {
    const float* obs    = (const float*)d_in[0];
    const float* alpha1 = (const float*)d_in[1];
    const float* beta1  = (const float*)d_in[2];
    const float* alpha2 = (const float*)d_in[3];
    const float* beta2  = (const float*)d_in[4];
    const float* mixw   = (const float*)d_in[5];

    const int Bn = in_sizes[1];
    const int Tn = in_sizes[0] / Bn;
    const size_t bt = (size_t)Bn * (size_t)Tn;

    const int EPB = BLOCK * VEC;
    if (Tn == 8 * EPB) {
        bbm_lag<8><<<Bn, BLOCK, 0, stream>>>(obs, alpha1, beta1, alpha2, beta2,
                                             mixw, (float*)d_out, Tn, bt);
    } else {
        bbm_kernel<<<Bn, BLOCK, 0, stream>>>(obs, alpha1, beta1, alpha2, beta2,
                                             mixw, (float*)d_out, Tn, bt);
    }
}